// Round 1
// baseline (29978.595 us; speedup 1.0000x reference)
//
#include <hip/hip_runtime.h>
#include <hip/hip_bf16.h>
#include <math.h>

#define L_ 4
#define B_ 4
#define S_ 1024
#define D_ 768
#define F_ 3072
#define E_ 4
#define V_ 256
#define H_ 12
#define DH_ 64
#define T_ (B_*S_)

__device__ __forceinline__ float gelu_f(float x) {
    // jax.nn.gelu(approximate=True): 0.5*x*(1+tanh(sqrt(2/pi)*(x+0.044715*x^3)))
    return 0.5f * x * (1.f + tanhf(0.7978845608028654f * (x + 0.044715f * x * x * x)));
}

// ---------------- embedding lookup into padded buffer [B][S+2][D] ----------------
__global__ __launch_bounds__(256) void embed_pad_k(const int* __restrict__ text,
                                                   const float* __restrict__ embed,
                                                   float* __restrict__ xpad) {
    int idx = blockIdx.x * 256 + threadIdx.x;
    const int tot = B_ * (S_ + 2) * D_;
    if (idx >= tot) return;
    int d = idx % D_;
    int sp = (idx / D_) % (S_ + 2);
    int b = idx / (D_ * (S_ + 2));
    float v = 0.f;
    if (sp >= 1 && sp <= S_) {
        int tok = text[b * S_ + sp - 1];
        v = embed[(long)tok * D_ + d];
    }
    xpad[idx] = v;
}

// conv_w [o][i][w] -> cw [(w*D+i)][o]  (so conv becomes GEMM with K=3*D)
__global__ __launch_bounds__(256) void repack_conv_k(const float* __restrict__ w,
                                                     float* __restrict__ cw) {
    int idx = blockIdx.x * 256 + threadIdx.x;
    if (idx >= 3 * D_ * D_) return;
    int o = idx % D_;
    int i = (idx / D_) % D_;
    int wi = idx / (D_ * D_);
    cw[idx] = w[((long)o * D_ + i) * 3 + wi];
}

__global__ __launch_bounds__(256) void conv_rows_k(int* __restrict__ r) {
    int t = blockIdx.x * 256 + threadIdx.x;
    if (t < T_) r[t] = t + 2 * (t / S_);   // row index into xpad (lda=D)
}

__global__ void zero_cnt_k(int* c) { if (threadIdx.x < L_ * E_) c[threadIdx.x] = 0; }

// ---------------- LayerNorm: one block per row, D=768 = 3 floats/thread ----------------
__global__ __launch_bounds__(256) void ln_k(const float* __restrict__ x,
                                            const float* __restrict__ g,
                                            const float* __restrict__ bb,
                                            float* __restrict__ out) {
    __shared__ float red[256];
    int row = blockIdx.x, tid = threadIdx.x;
    const float* xr = x + (long)row * D_;
    float v0 = xr[tid], v1 = xr[tid + 256], v2 = xr[tid + 512];
    red[tid] = v0 + v1 + v2; __syncthreads();
    for (int off = 128; off; off >>= 1) { if (tid < off) red[tid] += red[tid + off]; __syncthreads(); }
    float mean = red[0] * (1.f / D_);
    __syncthreads();
    float d0 = v0 - mean, d1 = v1 - mean, d2 = v2 - mean;
    red[tid] = d0 * d0 + d1 * d1 + d2 * d2; __syncthreads();
    for (int off = 128; off; off >>= 1) { if (tid < off) red[tid] += red[tid + off]; __syncthreads(); }
    float rs = rsqrtf(red[0] * (1.f / D_) + 1e-5f);
    float* orow = out + (long)row * D_;
    orow[tid]       = d0 * rs * g[tid]       + bb[tid];
    orow[tid + 256] = d1 * rs * g[tid + 256] + bb[tid + 256];
    orow[tid + 512] = d2 * rs * g[tid + 512] + bb[tid + 512];
}

// ---------------- generic fp32 GEMM: C = op(A_gathered @ B + bias) [+resid | scatter] ----------
// BM=128, BN=64, BK=16, 256 threads, 8x4 acc/thread.
#define BM 128
#define BN 64
#define BK 16
__global__ __launch_bounds__(256) void gemm_k(
    const float* __restrict__ A, const float* __restrict__ Bw,
    const float* __restrict__ bias, const float* __restrict__ resid,
    float* __restrict__ C,
    const int* __restrict__ a_rows, const int* __restrict__ res_rows,
    const int* __restrict__ m_ptr, int M, int N, int K,
    int lda, int ldc, int act,
    const int* __restrict__ scat_rows, const float* __restrict__ scat_scale)
{
    int Meff = m_ptr ? *m_ptr : M;
    int m0 = blockIdx.y * BM, n0 = blockIdx.x * BN;
    if (m0 >= Meff) return;
    __shared__ float As[BM][BK + 1];
    __shared__ float Bs[BK][BN];
    int tid = threadIdx.x;
    int arow_l = tid >> 1;            // 0..127
    int acol_l = (tid & 1) * 8;       // 0 or 8
    int brow_l = tid >> 4;            // 0..15
    int bcol_l = (tid & 15) * 4;      // 0..60
    int tx = tid & 15, ty = tid >> 4;
    float acc[8][4] = {};
    int grow = m0 + arow_l;
    bool aok = grow < Meff;
    long aoff = 0;
    if (aok) { int r = a_rows ? a_rows[grow] : grow; aoff = (long)r * lda; }

    for (int k0 = 0; k0 < K; k0 += BK) {
        float4 av0 = make_float4(0, 0, 0, 0), av1 = av0;
        if (aok) {
            const float* ap = A + aoff + k0 + acol_l;
            av0 = *(const float4*)ap;
            av1 = *(const float4*)(ap + 4);
        }
        As[arow_l][acol_l + 0] = av0.x; As[arow_l][acol_l + 1] = av0.y;
        As[arow_l][acol_l + 2] = av0.z; As[arow_l][acol_l + 3] = av0.w;
        As[arow_l][acol_l + 4] = av1.x; As[arow_l][acol_l + 5] = av1.y;
        As[arow_l][acol_l + 6] = av1.z; As[arow_l][acol_l + 7] = av1.w;
        float4 bv = make_float4(0, 0, 0, 0);
        int gb = n0 + bcol_l;
        if (gb < N) bv = *(const float4*)(Bw + (long)(k0 + brow_l) * N + gb);
        *(float4*)&Bs[brow_l][bcol_l] = bv;
        __syncthreads();
        #pragma unroll
        for (int kk = 0; kk < BK; ++kk) {
            float4 b4 = *(float4*)&Bs[kk][tx * 4];
            #pragma unroll
            for (int i = 0; i < 8; ++i) {
                float a = As[ty * 8 + i][kk];
                acc[i][0] += a * b4.x; acc[i][1] += a * b4.y;
                acc[i][2] += a * b4.z; acc[i][3] += a * b4.w;
            }
        }
        __syncthreads();
    }
    #pragma unroll
    for (int i = 0; i < 8; ++i) {
        int row = m0 + ty * 8 + i;
        if (row >= Meff) continue;
        #pragma unroll
        for (int j = 0; j < 4; ++j) {
            int col = n0 + tx * 4 + j;
            if (col >= N) continue;
            float v = acc[i][j];
            if (bias) v += bias[col];
            if (act == 1) v = gelu_f(v);
            if (scat_rows) {   // gate-weighted scatter-add (MoE FF2)
                int t = scat_rows[row];
                atomicAdd(&C[(long)t * ldc + col], scat_scale[row] * v);
            } else {
                if (resid) {
                    int rr = res_rows ? res_rows[row] : row;
                    v += resid[(long)rr * ldc + col];
                }
                C[(long)row * ldc + col] = v;
            }
        }
    }
}

// ---------------- attention: one block per (b,h,q). q/k/v in [B,S,(H,DH)] layout ----------------
__global__ __launch_bounds__(256) void attn_k(const float* __restrict__ Q,
                                              const float* __restrict__ Kb,
                                              const float* __restrict__ Vb,
                                              float* __restrict__ O) {
    __shared__ float sc[S_];
    __shared__ float qs[DH_];
    __shared__ float red[256];
    __shared__ float opart[4][DH_];
    int idx = blockIdx.x;
    int sq = idx % S_;
    int h = (idx / S_) % H_;
    int b = idx / (S_ * H_);
    int tid = threadIdx.x, lane = tid & 63, wave = tid >> 6;
    long base = ((long)b * S_) * D_ + h * DH_;
    if (tid < DH_) qs[tid] = Q[base + (long)sq * D_ + tid];
    __syncthreads();
    // scores: wave handles keys j = wave::4, lane = dim, shuffle-reduce the dot
    for (int j = wave; j < S_; j += 4) {
        float p = qs[lane] * Kb[base + (long)j * D_ + lane];
        #pragma unroll
        for (int off = 32; off; off >>= 1) p += __shfl_xor(p, off);
        if (lane == 0) sc[j] = p * 0.125f;   // 1/sqrt(64)
    }
    __syncthreads();
    float lm = -1e30f;
    for (int j = tid; j < S_; j += 256) lm = fmaxf(lm, sc[j]);
    red[tid] = lm; __syncthreads();
    for (int off = 128; off; off >>= 1) { if (tid < off) red[tid] = fmaxf(red[tid], red[tid + off]); __syncthreads(); }
    float mx = red[0]; __syncthreads();
    float ls = 0.f;
    for (int j = tid; j < S_; j += 256) { float e = __expf(sc[j] - mx); sc[j] = e; ls += e; }
    red[tid] = ls; __syncthreads();
    for (int off = 128; off; off >>= 1) { if (tid < off) red[tid] += red[tid + off]; __syncthreads(); }
    float inv = 1.f / red[0];
    __syncthreads();
    float acc = 0.f;
    for (int j = wave; j < S_; j += 4) acc += sc[j] * Vb[base + (long)j * D_ + lane];
    opart[wave][lane] = acc;
    __syncthreads();
    if (tid < DH_) {
        float o = (opart[0][tid] + opart[1][tid] + opart[2][tid] + opart[3][tid]) * inv;
        O[base + (long)sq * D_ + tid] = o;
    }
}

// ---------------- router: softmax(E=4) + top-2 + compaction lists ----------------
__global__ __launch_bounds__(256) void router_k(const float* __restrict__ logits,
                                                int* __restrict__ cnt,
                                                int* __restrict__ list,
                                                float* __restrict__ gate_slot) {
    int t = blockIdx.x * 256 + threadIdx.x;
    if (t >= T_) return;
    float l0 = logits[t * 4 + 0], l1 = logits[t * 4 + 1], l2 = logits[t * 4 + 2], l3 = logits[t * 4 + 3];
    float m = fmaxf(fmaxf(l0, l1), fmaxf(l2, l3));
    float p[4] = { __expf(l0 - m), __expf(l1 - m), __expf(l2 - m), __expf(l3 - m) };
    int i0 = 0; float v0p = p[0];
    #pragma unroll
    for (int e = 1; e < 4; ++e) if (p[e] > v0p) { v0p = p[e]; i0 = e; }   // strict > => lowest index on tie (jax top_k)
    int i1 = -1; float v1p = -1.f;
    #pragma unroll
    for (int e = 0; e < 4; ++e) { if (e == i0) continue; if (p[e] > v1p) { v1p = p[e]; i1 = e; } }
    float g0 = v0p / (v0p + v1p), g1 = v1p / (v0p + v1p);   // renormalized top-2 gates
    int pos0 = atomicAdd(&cnt[i0], 1);
    list[i0 * T_ + pos0] = t; gate_slot[i0 * T_ + pos0] = g0;
    int pos1 = atomicAdd(&cnt[i1], 1);
    list[i1 * T_ + pos1] = t; gate_slot[i1 * T_ + pos1] = g1;
}

extern "C" void kernel_launch(void* const* d_in, const int* in_sizes, int n_in,
                              void* d_out, int out_size, void* d_ws, size_t ws_size,
                              hipStream_t stream) {
    const int*   text   = (const int*)  d_in[0];
    const float* embed  = (const float*)d_in[1];
    const float* conv_w = (const float*)d_in[2];
    const float* conv_b = (const float*)d_in[3];
    const float* Wq = (const float*)d_in[4],  *bq = (const float*)d_in[5];
    const float* Wk = (const float*)d_in[6],  *bk = (const float*)d_in[7];
    const float* Wv = (const float*)d_in[8],  *bv = (const float*)d_in[9];
    const float* Wo = (const float*)d_in[10], *bo = (const float*)d_in[11];
    const float* rw = (const float*)d_in[12], *rb = (const float*)d_in[13];
    const float* ew1 = (const float*)d_in[14], *eb1 = (const float*)d_in[15];
    const float* ew2 = (const float*)d_in[16], *eb2 = (const float*)d_in[17];
    const float* ln1g = (const float*)d_in[18], *ln1b = (const float*)d_in[19];
    const float* ln2g = (const float*)d_in[20], *ln2b = (const float*)d_in[21];
    const float* lnfg = (const float*)d_in[22], *lnfb = (const float*)d_in[23];
    const float* outw = (const float*)d_in[24], *outb = (const float*)d_in[25];
    float* out = (float*)d_out;

    float* ws = (float*)d_ws;
    size_t o = 0;
    auto alloc = [&](size_t n) { float* p = ws + o; o += (n + 63) & ~(size_t)63; return p; };
    float* xpad = alloc((size_t)B_ * (S_ + 2) * D_);
    float* x    = alloc((size_t)T_ * D_);
    float* h    = alloc((size_t)T_ * D_);
    float* qb   = alloc((size_t)T_ * D_);
    float* kb   = alloc((size_t)T_ * D_);
    float* vb   = alloc((size_t)T_ * D_);
    float* ob   = alloc((size_t)T_ * D_);
    float* cw   = alloc((size_t)3 * D_ * D_);
    float* h1   = alloc((size_t)T_ * F_);
    float* probs = alloc((size_t)T_ * E_);
    float* gate_slot = alloc((size_t)E_ * T_);
    int* conv_rows = (int*)alloc(T_);
    int* list      = (int*)alloc((size_t)E_ * T_);
    int* cnt       = (int*)alloc(64);
    (void)ws_size; (void)in_sizes; (void)n_in; (void)out_size;

    zero_cnt_k<<<1, 64, 0, stream>>>(cnt);
    embed_pad_k<<<(B_ * (S_ + 2) * D_ + 255) / 256, 256, 0, stream>>>(text, embed, xpad);
    repack_conv_k<<<(3 * D_ * D_ + 255) / 256, 256, 0, stream>>>(conv_w, cw);
    conv_rows_k<<<(T_ + 255) / 256, 256, 0, stream>>>(conv_rows);
    // x = xemb + gelu(conv(xemb) + conv_b)   (GEMM over padded rows; residual = center column of xpad)
    gemm_k<<<dim3(D_ / BN, T_ / BM), 256, 0, stream>>>(
        xpad, cw, conv_b, xpad + D_, x,
        conv_rows, conv_rows, nullptr, T_, D_, 3 * D_, D_, D_, 1, nullptr, nullptr);

    for (int i = 0; i < L_; ++i) {
        ln_k<<<T_, 256, 0, stream>>>(x, ln1g + i * D_, ln1b + i * D_, h);
        gemm_k<<<dim3(D_ / BN, T_ / BM), 256, 0, stream>>>(
            h, Wq + (long)i * D_ * D_, bq + i * D_, nullptr, qb,
            nullptr, nullptr, nullptr, T_, D_, D_, D_, D_, 0, nullptr, nullptr);
        gemm_k<<<dim3(D_ / BN, T_ / BM), 256, 0, stream>>>(
            h, Wk + (long)i * D_ * D_, bk + i * D_, nullptr, kb,
            nullptr, nullptr, nullptr, T_, D_, D_, D_, D_, 0, nullptr, nullptr);
        gemm_k<<<dim3(D_ / BN, T_ / BM), 256, 0, stream>>>(
            h, Wv + (long)i * D_ * D_, bv + i * D_, nullptr, vb,
            nullptr, nullptr, nullptr, T_, D_, D_, D_, D_, 0, nullptr, nullptr);
        attn_k<<<B_ * H_ * S_, 256, 0, stream>>>(qb, kb, vb, ob);
        gemm_k<<<dim3(D_ / BN, T_ / BM), 256, 0, stream>>>(
            ob, Wo + (long)i * D_ * D_, bo + i * D_, x, x,
            nullptr, nullptr, nullptr, T_, D_, D_, D_, D_, 0, nullptr, nullptr);
        ln_k<<<T_, 256, 0, stream>>>(x, ln2g + i * D_, ln2b + i * D_, h);
        gemm_k<<<dim3(1, T_ / BM), 256, 0, stream>>>(
            h, rw + (long)i * D_ * E_, rb + i * E_, nullptr, probs,
            nullptr, nullptr, nullptr, T_, E_, D_, D_, E_, 0, nullptr, nullptr);
        router_k<<<T_ / 256, 256, 0, stream>>>(probs, cnt + i * E_, list, gate_slot);
        for (int e = 0; e < E_; ++e) {
            const float* w1 = ew1 + ((long)i * E_ + e) * D_ * F_;
            const float* b1 = eb1 + ((long)i * E_ + e) * F_;
            const float* w2 = ew2 + ((long)i * E_ + e) * F_ * D_;
            const float* b2 = eb2 + ((long)i * E_ + e) * D_;
            // FF1: h1 = gelu(h[list] @ w1 + b1), M = cnt[e] (device-side)
            gemm_k<<<dim3(F_ / BN, T_ / BM), 256, 0, stream>>>(
                h, w1, b1, nullptr, h1,
                list + e * T_, nullptr, cnt + i * E_ + e, T_, F_, D_, D_, F_, 1, nullptr, nullptr);
            // FF2: x[tok] += gate * (h1 @ w2 + b2)  (scatter-add)
            gemm_k<<<dim3(D_ / BN, T_ / BM), 256, 0, stream>>>(
                h1, w2, b2, nullptr, x,
                nullptr, nullptr, cnt + i * E_ + e, T_, D_, F_, F_, D_, 0,
                list + e * T_, gate_slot + e * T_);
        }
    }
    ln_k<<<T_, 256, 0, stream>>>(x, lnfg, lnfb, h);
    gemm_k<<<dim3(V_ / BN, T_ / BM), 256, 0, stream>>>(
        h, outw, outb, nullptr, out,
        nullptr, nullptr, nullptr, T_, V_, D_, D_, V_, 0, nullptr, nullptr);
}

// Round 2
// 12483.904 us; speedup vs baseline: 2.4014x; 2.4014x over previous
//
#include <hip/hip_runtime.h>
#include <hip/hip_bf16.h>
#include <math.h>

#define L_ 4
#define B_ 4
#define S_ 1024
#define D_ 768
#define F_ 3072
#define E_ 4
#define V_ 256
#define H_ 12
#define DH_ 64
#define T_ (B_*S_)

__device__ __forceinline__ float gelu_f(float x) {
    return 0.5f * x * (1.f + tanhf(0.7978845608028654f * (x + 0.044715f * x * x * x)));
}

// ---------------- embedding lookup into padded buffer [B][S+2][D] ----------------
__global__ __launch_bounds__(256) void embed_pad_k(const int* __restrict__ text,
                                                   const float* __restrict__ embed,
                                                   float* __restrict__ xpad) {
    int idx = blockIdx.x * 256 + threadIdx.x;
    const int tot = B_ * (S_ + 2) * D_;
    if (idx >= tot) return;
    int d = idx % D_;
    int sp = (idx / D_) % (S_ + 2);
    int b = idx / (D_ * (S_ + 2));
    float v = 0.f;
    if (sp >= 1 && sp <= S_) {
        int tok = text[b * S_ + sp - 1];
        v = embed[(long)tok * D_ + d];
    }
    xpad[idx] = v;
}

// conv_w [o][i][w] -> cw [(w*D+i)][o]
__global__ __launch_bounds__(256) void repack_conv_k(const float* __restrict__ w,
                                                     float* __restrict__ cw) {
    int idx = blockIdx.x * 256 + threadIdx.x;
    if (idx >= 3 * D_ * D_) return;
    int o = idx % D_;
    int i = (idx / D_) % D_;
    int wi = idx / (D_ * D_);
    cw[idx] = w[((long)o * D_ + i) * 3 + wi];
}

__global__ __launch_bounds__(256) void conv_rows_k(int* __restrict__ r) {
    int t = blockIdx.x * 256 + threadIdx.x;
    if (t < T_) r[t] = t + 2 * (t / S_);
}

__global__ void zero_cnt_k(int* c) { if (threadIdx.x < L_ * E_) c[threadIdx.x] = 0; }

// ---------------- LayerNorm ----------------
__global__ __launch_bounds__(256) void ln_k(const float* __restrict__ x,
                                            const float* __restrict__ g,
                                            const float* __restrict__ bb,
                                            float* __restrict__ out) {
    __shared__ float red[256];
    int row = blockIdx.x, tid = threadIdx.x;
    const float* xr = x + (long)row * D_;
    float v0 = xr[tid], v1 = xr[tid + 256], v2 = xr[tid + 512];
    red[tid] = v0 + v1 + v2; __syncthreads();
    for (int off = 128; off; off >>= 1) { if (tid < off) red[tid] += red[tid + off]; __syncthreads(); }
    float mean = red[0] * (1.f / D_);
    __syncthreads();
    float d0 = v0 - mean, d1 = v1 - mean, d2 = v2 - mean;
    red[tid] = d0 * d0 + d1 * d1 + d2 * d2; __syncthreads();
    for (int off = 128; off; off >>= 1) { if (tid < off) red[tid] += red[tid + off]; __syncthreads(); }
    float rs = rsqrtf(red[0] * (1.f / D_) + 1e-5f);
    float* orow = out + (long)row * D_;
    orow[tid]       = d0 * rs * g[tid]       + bb[tid];
    orow[tid + 256] = d1 * rs * g[tid + 256] + bb[tid + 256];
    orow[tid + 512] = d2 * rs * g[tid + 512] + bb[tid + 512];
}

// ---------------- generic fp32 GEMM (unchanged from R1) ----------------
#define BM 128
#define BN 64
#define BK 16
__global__ __launch_bounds__(256) void gemm_k(
    const float* __restrict__ A, const float* __restrict__ Bw,
    const float* __restrict__ bias, const float* __restrict__ resid,
    float* __restrict__ C,
    const int* __restrict__ a_rows, const int* __restrict__ res_rows,
    const int* __restrict__ m_ptr, int M, int N, int K,
    int lda, int ldc, int act,
    const int* __restrict__ scat_rows, const float* __restrict__ scat_scale)
{
    int Meff = m_ptr ? *m_ptr : M;
    int m0 = blockIdx.y * BM, n0 = blockIdx.x * BN;
    if (m0 >= Meff) return;
    __shared__ float As[BM][BK + 1];
    __shared__ float Bs[BK][BN];
    int tid = threadIdx.x;
    int arow_l = tid >> 1;
    int acol_l = (tid & 1) * 8;
    int brow_l = tid >> 4;
    int bcol_l = (tid & 15) * 4;
    int tx = tid & 15, ty = tid >> 4;
    float acc[8][4] = {};
    int grow = m0 + arow_l;
    bool aok = grow < Meff;
    long aoff = 0;
    if (aok) { int r = a_rows ? a_rows[grow] : grow; aoff = (long)r * lda; }

    for (int k0 = 0; k0 < K; k0 += BK) {
        float4 av0 = make_float4(0, 0, 0, 0), av1 = av0;
        if (aok) {
            const float* ap = A + aoff + k0 + acol_l;
            av0 = *(const float4*)ap;
            av1 = *(const float4*)(ap + 4);
        }
        As[arow_l][acol_l + 0] = av0.x; As[arow_l][acol_l + 1] = av0.y;
        As[arow_l][acol_l + 2] = av0.z; As[arow_l][acol_l + 3] = av0.w;
        As[arow_l][acol_l + 4] = av1.x; As[arow_l][acol_l + 5] = av1.y;
        As[arow_l][acol_l + 6] = av1.z; As[arow_l][acol_l + 7] = av1.w;
        float4 bv = make_float4(0, 0, 0, 0);
        int gb = n0 + bcol_l;
        if (gb < N) bv = *(const float4*)(Bw + (long)(k0 + brow_l) * N + gb);
        *(float4*)&Bs[brow_l][bcol_l] = bv;
        __syncthreads();
        #pragma unroll
        for (int kk = 0; kk < BK; ++kk) {
            float4 b4 = *(float4*)&Bs[kk][tx * 4];
            #pragma unroll
            for (int i = 0; i < 8; ++i) {
                float a = As[ty * 8 + i][kk];
                acc[i][0] += a * b4.x; acc[i][1] += a * b4.y;
                acc[i][2] += a * b4.z; acc[i][3] += a * b4.w;
            }
        }
        __syncthreads();
    }
    #pragma unroll
    for (int i = 0; i < 8; ++i) {
        int row = m0 + ty * 8 + i;
        if (row >= Meff) continue;
        #pragma unroll
        for (int j = 0; j < 4; ++j) {
            int col = n0 + tx * 4 + j;
            if (col >= N) continue;
            float v = acc[i][j];
            if (bias) v += bias[col];
            if (act == 1) v = gelu_f(v);
            if (scat_rows) {
                int t = scat_rows[row];
                atomicAdd(&C[(long)t * ldc + col], scat_scale[row] * v);
            } else {
                if (resid) {
                    int rr = res_rows ? res_rows[row] : row;
                    v += resid[(long)rr * ldc + col];
                }
                C[(long)row * ldc + col] = v;
            }
        }
    }
}

// ---------------- flash attention: one block per (b,h,64-query tile) ----------------
// LDS: Qt [d][q] (whole block), KP = union{ Kt [d][k] | Pt [q][k] }, Vs [k][d].
// 256 threads as 16x16; each thread owns a 4q x 4k score block and 4q x 4d output block.
#define FA_PAD 68
__global__ __launch_bounds__(256) void flash_attn_k(const float* __restrict__ Q,
                                                    const float* __restrict__ Kb,
                                                    const float* __restrict__ Vb,
                                                    float* __restrict__ O) {
    __shared__ float Qt[64][FA_PAD];
    __shared__ float KP[64][FA_PAD];
    __shared__ float Vs[64][FA_PAD];
    int blk = blockIdx.x;
    int qt = blk & 15;                  // S_/64 = 16
    int h  = (blk >> 4) % H_;
    int b  = blk / (16 * H_);
    int q0 = qt * 64;
    long base = ((long)b * S_) * D_ + h * DH_;
    int tid = threadIdx.x;
    int tx = tid & 15, ty = tid >> 4;
    int j = tid >> 2, c0 = (tid & 3) * 16;   // staging: row j, 16-float chunk c0

    // ---- load Q tile transposed: Qt[d][q] ----
    {
        const float* qp = Q + base + (long)(q0 + j) * D_ + c0;
        #pragma unroll
        for (int m = 0; m < 16; m += 4) {
            float4 v = *(const float4*)(qp + m);
            Qt[c0 + m + 0][j] = v.x; Qt[c0 + m + 1][j] = v.y;
            Qt[c0 + m + 2][j] = v.z; Qt[c0 + m + 3][j] = v.w;
        }
    }
    float o[4][4] = {};
    float mprev[4] = {-1e30f, -1e30f, -1e30f, -1e30f};
    float l[4] = {0.f, 0.f, 0.f, 0.f};

    for (int k0 = 0; k0 < S_; k0 += 64) {
        __syncthreads();   // previous tile's Pt/Vs reads done
        // ---- stage K (transposed) and V (natural) ----
        {
            const float* kp = Kb + base + (long)(k0 + j) * D_ + c0;
            #pragma unroll
            for (int m = 0; m < 16; m += 4) {
                float4 v = *(const float4*)(kp + m);
                KP[c0 + m + 0][j] = v.x; KP[c0 + m + 1][j] = v.y;
                KP[c0 + m + 2][j] = v.z; KP[c0 + m + 3][j] = v.w;
            }
            const float* vp = Vb + base + (long)(k0 + j) * D_ + c0;
            #pragma unroll
            for (int m = 0; m < 16; m += 4) {
                *(float4*)&Vs[j][c0 + m] = *(const float4*)(vp + m);
            }
        }
        __syncthreads();
        // ---- scores: s[4][4] over d, Qt broadcast-read, Kt coalesced-read ----
        float s[4][4] = {};
        #pragma unroll 8
        for (int d = 0; d < 64; ++d) {
            float4 qv = *(float4*)&Qt[d][ty * 4];
            float4 kv = *(float4*)&KP[d][tx * 4];
            s[0][0] += qv.x * kv.x; s[0][1] += qv.x * kv.y; s[0][2] += qv.x * kv.z; s[0][3] += qv.x * kv.w;
            s[1][0] += qv.y * kv.x; s[1][1] += qv.y * kv.y; s[1][2] += qv.y * kv.z; s[1][3] += qv.y * kv.w;
            s[2][0] += qv.z * kv.x; s[2][1] += qv.z * kv.y; s[2][2] += qv.z * kv.z; s[2][3] += qv.z * kv.w;
            s[3][0] += qv.w * kv.x; s[3][1] += qv.w * kv.y; s[3][2] += qv.w * kv.z; s[3][3] += qv.w * kv.w;
        }
        // ---- online softmax (16-lane butterfly per query row) ----
        float alpha[4];
        #pragma unroll
        for (int i = 0; i < 4; ++i) {
            s[i][0] *= 0.125f; s[i][1] *= 0.125f; s[i][2] *= 0.125f; s[i][3] *= 0.125f;
            float mloc = fmaxf(fmaxf(s[i][0], s[i][1]), fmaxf(s[i][2], s[i][3]));
            #pragma unroll
            for (int off = 1; off < 16; off <<= 1) mloc = fmaxf(mloc, __shfl_xor(mloc, off));
            float mnew = fmaxf(mprev[i], mloc);
            alpha[i] = __expf(mprev[i] - mnew);
            s[i][0] = __expf(s[i][0] - mnew); s[i][1] = __expf(s[i][1] - mnew);
            s[i][2] = __expf(s[i][2] - mnew); s[i][3] = __expf(s[i][3] - mnew);
            float rs = s[i][0] + s[i][1] + s[i][2] + s[i][3];
            #pragma unroll
            for (int off = 1; off < 16; off <<= 1) rs += __shfl_xor(rs, off);
            l[i] = l[i] * alpha[i] + rs;
            mprev[i] = mnew;
            o[i][0] *= alpha[i]; o[i][1] *= alpha[i]; o[i][2] *= alpha[i]; o[i][3] *= alpha[i];
        }
        __syncthreads();   // all Kt reads done before overwriting as Pt
        // ---- write P tile: Pt[q][k] ----
        #pragma unroll
        for (int i = 0; i < 4; ++i)
            *(float4*)&KP[ty * 4 + i][tx * 4] = make_float4(s[i][0], s[i][1], s[i][2], s[i][3]);
        __syncthreads();
        // ---- PV accumulate: o[q][d] += P[q][k] * V[k][d] ----
        #pragma unroll 4
        for (int kk = 0; kk < 64; kk += 4) {
            float4 pr[4];
            #pragma unroll
            for (int i = 0; i < 4; ++i) pr[i] = *(float4*)&KP[ty * 4 + i][kk];
            #pragma unroll
            for (int e = 0; e < 4; ++e) {
                float4 vv = *(float4*)&Vs[kk + e][tx * 4];
                float pe0 = e == 0 ? pr[0].x : e == 1 ? pr[0].y : e == 2 ? pr[0].z : pr[0].w;
                float pe1 = e == 0 ? pr[1].x : e == 1 ? pr[1].y : e == 2 ? pr[1].z : pr[1].w;
                float pe2 = e == 0 ? pr[2].x : e == 1 ? pr[2].y : e == 2 ? pr[2].z : pr[2].w;
                float pe3 = e == 0 ? pr[3].x : e == 1 ? pr[3].y : e == 2 ? pr[3].z : pr[3].w;
                o[0][0] += pe0 * vv.x; o[0][1] += pe0 * vv.y; o[0][2] += pe0 * vv.z; o[0][3] += pe0 * vv.w;
                o[1][0] += pe1 * vv.x; o[1][1] += pe1 * vv.y; o[1][2] += pe1 * vv.z; o[1][3] += pe1 * vv.w;
                o[2][0] += pe2 * vv.x; o[2][1] += pe2 * vv.y; o[2][2] += pe2 * vv.z; o[2][3] += pe2 * vv.w;
                o[3][0] += pe3 * vv.x; o[3][1] += pe3 * vv.y; o[3][2] += pe3 * vv.z; o[3][3] += pe3 * vv.w;
            }
        }
    }
    // ---- epilogue: normalize and store ----
    #pragma unroll
    for (int i = 0; i < 4; ++i) {
        float inv = 1.f / l[i];
        float4 ov = make_float4(o[i][0] * inv, o[i][1] * inv, o[i][2] * inv, o[i][3] * inv);
        *(float4*)(O + base + (long)(q0 + ty * 4 + i) * D_ + tx * 4) = ov;
    }
}

// ---------------- router ----------------
__global__ __launch_bounds__(256) void router_k(const float* __restrict__ logits,
                                                int* __restrict__ cnt,
                                                int* __restrict__ list,
                                                float* __restrict__ gate_slot) {
    int t = blockIdx.x * 256 + threadIdx.x;
    if (t >= T_) return;
    float l0 = logits[t * 4 + 0], l1 = logits[t * 4 + 1], l2 = logits[t * 4 + 2], l3 = logits[t * 4 + 3];
    float m = fmaxf(fmaxf(l0, l1), fmaxf(l2, l3));
    float p[4] = { __expf(l0 - m), __expf(l1 - m), __expf(l2 - m), __expf(l3 - m) };
    int i0 = 0; float v0p = p[0];
    #pragma unroll
    for (int e = 1; e < 4; ++e) if (p[e] > v0p) { v0p = p[e]; i0 = e; }
    int i1 = -1; float v1p = -1.f;
    #pragma unroll
    for (int e = 0; e < 4; ++e) { if (e == i0) continue; if (p[e] > v1p) { v1p = p[e]; i1 = e; } }
    float g0 = v0p / (v0p + v1p), g1 = v1p / (v0p + v1p);
    int pos0 = atomicAdd(&cnt[i0], 1);
    list[i0 * T_ + pos0] = t; gate_slot[i0 * T_ + pos0] = g0;
    int pos1 = atomicAdd(&cnt[i1], 1);
    list[i1 * T_ + pos1] = t; gate_slot[i1 * T_ + pos1] = g1;
}

extern "C" void kernel_launch(void* const* d_in, const int* in_sizes, int n_in,
                              void* d_out, int out_size, void* d_ws, size_t ws_size,
                              hipStream_t stream) {
    const int*   text   = (const int*)  d_in[0];
    const float* embed  = (const float*)d_in[1];
    const float* conv_w = (const float*)d_in[2];
    const float* conv_b = (const float*)d_in[3];
    const float* Wq = (const float*)d_in[4],  *bq = (const float*)d_in[5];
    const float* Wk = (const float*)d_in[6],  *bk = (const float*)d_in[7];
    const float* Wv = (const float*)d_in[8],  *bv = (const float*)d_in[9];
    const float* Wo = (const float*)d_in[10], *bo = (const float*)d_in[11];
    const float* rw = (const float*)d_in[12], *rb = (const float*)d_in[13];
    const float* ew1 = (const float*)d_in[14], *eb1 = (const float*)d_in[15];
    const float* ew2 = (const float*)d_in[16], *eb2 = (const float*)d_in[17];
    const float* ln1g = (const float*)d_in[18], *ln1b = (const float*)d_in[19];
    const float* ln2g = (const float*)d_in[20], *ln2b = (const float*)d_in[21];
    const float* lnfg = (const float*)d_in[22], *lnfb = (const float*)d_in[23];
    const float* outw = (const float*)d_in[24], *outb = (const float*)d_in[25];
    float* out = (float*)d_out;

    float* ws = (float*)d_ws;
    size_t o = 0;
    auto alloc = [&](size_t n) { float* p = ws + o; o += (n + 63) & ~(size_t)63; return p; };
    float* xpad = alloc((size_t)B_ * (S_ + 2) * D_);
    float* x    = alloc((size_t)T_ * D_);
    float* h    = alloc((size_t)T_ * D_);
    float* qb   = alloc((size_t)T_ * D_);
    float* kb   = alloc((size_t)T_ * D_);
    float* vb   = alloc((size_t)T_ * D_);
    float* ob   = alloc((size_t)T_ * D_);
    float* cw   = alloc((size_t)3 * D_ * D_);
    float* h1   = alloc((size_t)T_ * F_);
    float* probs = alloc((size_t)T_ * E_);
    float* gate_slot = alloc((size_t)E_ * T_);
    int* conv_rows = (int*)alloc(T_);
    int* list      = (int*)alloc((size_t)E_ * T_);
    int* cnt       = (int*)alloc(64);
    (void)ws_size; (void)in_sizes; (void)n_in; (void)out_size;

    zero_cnt_k<<<1, 64, 0, stream>>>(cnt);
    embed_pad_k<<<(B_ * (S_ + 2) * D_ + 255) / 256, 256, 0, stream>>>(text, embed, xpad);
    repack_conv_k<<<(3 * D_ * D_ + 255) / 256, 256, 0, stream>>>(conv_w, cw);
    conv_rows_k<<<(T_ + 255) / 256, 256, 0, stream>>>(conv_rows);
    gemm_k<<<dim3(D_ / BN, T_ / BM), 256, 0, stream>>>(
        xpad, cw, conv_b, xpad + D_, x,
        conv_rows, conv_rows, nullptr, T_, D_, 3 * D_, D_, D_, 1, nullptr, nullptr);

    for (int i = 0; i < L_; ++i) {
        ln_k<<<T_, 256, 0, stream>>>(x, ln1g + i * D_, ln1b + i * D_, h);
        gemm_k<<<dim3(D_ / BN, T_ / BM), 256, 0, stream>>>(
            h, Wq + (long)i * D_ * D_, bq + i * D_, nullptr, qb,
            nullptr, nullptr, nullptr, T_, D_, D_, D_, D_, 0, nullptr, nullptr);
        gemm_k<<<dim3(D_ / BN, T_ / BM), 256, 0, stream>>>(
            h, Wk + (long)i * D_ * D_, bk + i * D_, nullptr, kb,
            nullptr, nullptr, nullptr, T_, D_, D_, D_, D_, 0, nullptr, nullptr);
        gemm_k<<<dim3(D_ / BN, T_ / BM), 256, 0, stream>>>(
            h, Wv + (long)i * D_ * D_, bv + i * D_, nullptr, vb,
            nullptr, nullptr, nullptr, T_, D_, D_, D_, D_, 0, nullptr, nullptr);
        flash_attn_k<<<B_ * H_ * (S_ / 64), 256, 0, stream>>>(qb, kb, vb, ob);
        gemm_k<<<dim3(D_ / BN, T_ / BM), 256, 0, stream>>>(
            ob, Wo + (long)i * D_ * D_, bo + i * D_, x, x,
            nullptr, nullptr, nullptr, T_, D_, D_, D_, D_, 0, nullptr, nullptr);
        ln_k<<<T_, 256, 0, stream>>>(x, ln2g + i * D_, ln2b + i * D_, h);
        gemm_k<<<dim3(1, T_ / BM), 256, 0, stream>>>(
            h, rw + (long)i * D_ * E_, rb + i * E_, nullptr, probs,
            nullptr, nullptr, nullptr, T_, E_, D_, D_, E_, 0, nullptr, nullptr);
        router_k<<<T_ / 256, 256, 0, stream>>>(probs, cnt + i * E_, list, gate_slot);
        for (int e = 0; e < E_; ++e) {
            const float* w1 = ew1 + ((long)i * E_ + e) * D_ * F_;
            const float* b1 = eb1 + ((long)i * E_ + e) * F_;
            const float* w2 = ew2 + ((long)i * E_ + e) * F_ * D_;
            const float* b2 = eb2 + ((long)i * E_ + e) * D_;
            gemm_k<<<dim3(F_ / BN, T_ / BM), 256, 0, stream>>>(
                h, w1, b1, nullptr, h1,
                list + e * T_, nullptr, cnt + i * E_ + e, T_, F_, D_, D_, F_, 1, nullptr, nullptr);
            gemm_k<<<dim3(D_ / BN, T_ / BM), 256, 0, stream>>>(
                h1, w2, b2, nullptr, x,
                nullptr, nullptr, cnt + i * E_ + e, T_, D_, F_, F_, D_, 0,
                list + e * T_, gate_slot + e * T_);
        }
    }
    ln_k<<<T_, 256, 0, stream>>>(x, lnfg, lnfb, h);
    gemm_k<<<dim3(V_ / BN, T_ / BM), 256, 0, stream>>>(
        h, outw, outb, nullptr, out,
        nullptr, nullptr, nullptr, T_, V_, D_, D_, V_, 0, nullptr, nullptr);
}